// Round 2
// baseline (590.460 us; speedup 1.0000x reference)
//
#include <hip/hip_runtime.h>
#include <stdint.h>

// Problem constants
#define T_STEPS 512
#define HID     64
#define INP     10
#define MB      16          // samples per block
#define KS      88          // k-stride (elements) of packed W layout [t][n][KS]
#define HS      72          // h LDS row stride (elems) : 144B, 16B-aligned, 2-way banks (free)
#define XS      40          // x LDS row stride (elems) : 80B, 16B-aligned, 2-way banks (free)
#define WT_ELEMS (HID*KS)   // 5632 bf16 per step
#define WT_BYTES (WT_ELEMS*2)  // 11264 B per step
#define WS_SLOTS (WT_BYTES/16) // 704 16B slots

typedef float  f32x4  __attribute__((ext_vector_type(4)));
typedef short  s16x8  __attribute__((ext_vector_type(8)));
typedef __bf16 bf16x8 __attribute__((ext_vector_type(8)));

__device__ __forceinline__ short f2bf(float f) {
    unsigned u = __builtin_bit_cast(unsigned, f);
    u = (u + 0x7FFFu + ((u >> 16) & 1u)) >> 16;   // RNE
    return (short)u;
}
__device__ __forceinline__ float bf2f(short s) {
    unsigned u = ((unsigned)(unsigned short)s) << 16;
    return __builtin_bit_cast(float, u);
}

// ---------------------------------------------------------------------------
// Pre-pass: pack [W_hh[t] (64x64) ; W_xh[t] (10x64) ; zeros] transposed into
// bf16 Wc[t][n][k] with k-stride 88 (k<64: Whh[k][n], 64..73: Wxh[k-64][n],
// 74..87: 0). One block per t; coalesced read via LDS transpose.
// ---------------------------------------------------------------------------
__global__ __launch_bounds__(256) void prep_w(const float* __restrict__ Wxh,
                                              const float* __restrict__ Whh,
                                              short* __restrict__ Wc) {
    __shared__ float s_hh[64 * 64];
    __shared__ float s_xh[INP * 64];
    const int t = blockIdx.x, tid = threadIdx.x;
    for (int i = tid; i < 64 * 64; i += 256) s_hh[i] = Whh[t * 4096 + i];
    for (int i = tid; i < INP * 64; i += 256) s_xh[i] = Wxh[t * (INP * 64) + i];
    __syncthreads();
    short* dst = Wc + (size_t)t * WT_ELEMS;
    for (int i = tid; i < WT_ELEMS; i += 256) {
        const int n = i / KS, k = i % KS;
        float v = 0.f;
        if (k < 64)      v = s_hh[k * 64 + n];
        else if (k < 74) v = s_xh[(k - 64) * 64 + n];
        dst[i] = f2bf(v);
    }
}

// ---------------------------------------------------------------------------
// Main recurrence kernel. 512 blocks x 256 threads, MB=16 samples per block.
// Per step: one 16x(64)x(K=96) GEMM via 3x mfma_f32_16x16x32_bf16 per wave
// (wave w owns N-tile w). One barrier per step; W and x double-buffered.
// ---------------------------------------------------------------------------
__global__ __launch_bounds__(256, 2) void rnn_main(const float* __restrict__ X,
                                                   const int* __restrict__ L,
                                                   const short* __restrict__ Wc,
                                                   const float* __restrict__ Wlin,
                                                   const float* __restrict__ blin,
                                                   float* __restrict__ out) {
    __shared__ __attribute__((aligned(16))) short Wb[2][WT_ELEMS + 16];
    __shared__ __attribute__((aligned(16))) short hb[2][MB * HS];
    __shared__ __attribute__((aligned(16))) short xb[2][MB * XS];
    __shared__ int len_s[MB];

    const int tid  = threadIdx.x;
    const int lane = tid & 63;
    const int wv   = tid >> 6;        // wave id 0..3 -> N-tile
    const int q    = lane >> 4;       // lane quad
    const int l    = lane & 15;
    const long long bbase = (long long)blockIdx.x * MB;

    // ---- init: zero h0, zero x pads, zero Wb overrun pad, stage lengths ----
    for (int i = tid; i < MB * HS; i += 256) hb[0][i] = 0;
    for (int i = tid; i < MB * XS; i += 256) { xb[0][i] = 0; xb[1][i] = 0; }
    if (tid < 16) { Wb[0][WT_ELEMS + tid] = 0; Wb[1][WT_ELEMS + tid] = 0; }
    if (tid < MB) len_s[tid] = L[bbase + tid];     // int32! (harness passes int)
    __syncthreads();

    // ---- pre-stage W[0] (async -> Wb[0]) and x[0] (-> xb[0]), x[1] -> reg ----
    {
        const char* src = (const char*)(Wc);
        char* dst = (char*)&Wb[0][0];
#pragma unroll
        for (int i = 0; i < 3; ++i) {
            const int slot = tid + i * 256;
            if (slot < WS_SLOTS)
                __builtin_amdgcn_global_load_lds(
                    (const __attribute__((address_space(1))) unsigned int*)(src + slot * 16),
                    (__attribute__((address_space(3))) unsigned int*)(dst + slot * 16),
                    16, 0, 0);
        }
    }
    const int xs = tid / INP, xi = tid % INP;   // valid when tid < 160
    float xreg = 0.f;
    if (tid < MB * INP) {
        xb[0][xs * XS + xi] = f2bf(X[(bbase + xs) * (T_STEPS * INP) + 0 * INP + xi]);
        xreg = X[(bbase + xs) * (T_STEPS * INP) + 1 * INP + xi];   // x[1]
    }
    __syncthreads();   // drains the global_load_lds too

    // per-lane persistent state: C-layout h copy + lengths for its 4 rows
    float hc[4] = {0.f, 0.f, 0.f, 0.f};
    int len4[4];
#pragma unroll
    for (int r = 0; r < 4; ++r) len4[r] = len_s[q * 4 + r];
    const int colw = wv * 16 + l;               // global hidden column owned

    for (int t = 0; t < T_STEPS; ++t) {
        const int cur = t & 1, nxt = cur ^ 1;

        // async prefetch W[t+1] into the other buffer (issues immediately)
        if (t + 1 < T_STEPS) {
            const char* src = (const char*)(Wc) + (size_t)(t + 1) * WT_BYTES;
            char* dst = (char*)&Wb[nxt][0];
#pragma unroll
            for (int i = 0; i < 3; ++i) {
                const int slot = tid + i * 256;
                if (slot < WS_SLOTS)
                    __builtin_amdgcn_global_load_lds(
                        (const __attribute__((address_space(1))) unsigned int*)(src + slot * 16),
                        (__attribute__((address_space(3))) unsigned int*)(dst + slot * 16),
                        16, 0, 0);
            }
        }

        // ---- x pipeline first (independent of MFMA): stage x[t+1], load x[t+2]
        if (tid < MB * INP) {
            xb[nxt][xs * XS + xi] = f2bf(xreg);
            if (t + 2 < T_STEPS)
                xreg = X[(bbase + xs) * (T_STEPS * INP) + (long long)(t + 2) * INP + xi];
        }

        // ---- fragments: A = [h | x], B = packed W (transposed layout) ----
        const s16x8 a0 = *(const s16x8*)&hb[cur][l * HS + q * 8];
        const s16x8 a1 = *(const s16x8*)&hb[cur][l * HS + 32 + q * 8];
        const s16x8 a2 = *(const s16x8*)&xb[cur][l * XS + q * 8];
        const s16x8 b0 = *(const s16x8*)&Wb[cur][colw * KS + q * 8];
        const s16x8 b1 = *(const s16x8*)&Wb[cur][colw * KS + 32 + q * 8];
        const s16x8 b2 = *(const s16x8*)&Wb[cur][colw * KS + 64 + q * 8];

        // three INDEPENDENT accumulators -> MFMA latencies overlap
        f32x4 z = {0.f, 0.f, 0.f, 0.f};
        f32x4 acc0 = __builtin_amdgcn_mfma_f32_16x16x32_bf16(
                  __builtin_bit_cast(bf16x8, a0), __builtin_bit_cast(bf16x8, b0), z, 0, 0, 0);
        f32x4 acc1 = __builtin_amdgcn_mfma_f32_16x16x32_bf16(
                  __builtin_bit_cast(bf16x8, a1), __builtin_bit_cast(bf16x8, b1), z, 0, 0, 0);
        f32x4 acc2 = __builtin_amdgcn_mfma_f32_16x16x32_bf16(
                  __builtin_bit_cast(bf16x8, a2), __builtin_bit_cast(bf16x8, b2), z, 0, 0, 0);

        // ---- tanh + freeze-select + write h[t+1] into next buffer ----
#pragma unroll
        for (int r = 0; r < 4; ++r) {
            const float a  = acc0[r] + acc1[r] + acc2[r];
            const float e  = __expf(2.f * a);
            const float th = 1.f - 2.f * __builtin_amdgcn_rcpf(e + 1.f);
            hc[r] = (t < len4[r]) ? th : hc[r];                 // freeze past length
            hb[nxt][(q * 4 + r) * HS + colw] = f2bf(hc[r]);     // C row = q*4+r
        }
        __syncthreads();
    }

    // ---- epilogue: out[b] = h_final . W_lin + b_lin  (final h in hb[0]) ----
    const float wl = Wlin[lane];
    const float bl = blin[0];
#pragma unroll
    for (int it = 0; it < 4; ++it) {
        const int s = wv + it * 4;
        float v = bf2f(hb[0][s * HS + lane]) * wl;
#pragma unroll
        for (int off = 32; off > 0; off >>= 1) v += __shfl_down(v, off);
        if (lane == 0) out[bbase + s] = v + bl;
    }
}

extern "C" void kernel_launch(void* const* d_in, const int* in_sizes, int n_in,
                              void* d_out, int out_size, void* d_ws, size_t ws_size,
                              hipStream_t stream) {
    const float* X    = (const float*)d_in[0];      // [B,T,10] fp32
    const int*   L    = (const int*)d_in[1];        // [B] int32 (harness int convention)
    const float* Wxh  = (const float*)d_in[2];      // [T,10,64]
    const float* Whh  = (const float*)d_in[3];      // [T,64,64]
    const float* Wlin = (const float*)d_in[4];      // [64,1]
    const float* blin = (const float*)d_in[5];      // [1]
    float*       out  = (float*)d_out;              // [B,1] fp32
    short*       Wc   = (short*)d_ws;               // 512*5632 bf16 = 5.77 MB

    prep_w<<<T_STEPS, 256, 0, stream>>>(Wxh, Whh, Wc);
    rnn_main<<<8192 / MB, 256, 0, stream>>>(X, L, Wc, Wlin, blin, out);
}